// Round 5
// baseline (3061.979 us; speedup 1.0000x reference)
//
#include <hip/hip_runtime.h>
#include <hip/hip_bf16.h>
#include <cstdint>

#define N_NODES 100000
#define N_EDGES 1600000
#define F_IN    512
#define F_HID   128
#define F_OUT   40
#define F_OUT_PAD 48

#define BSZ      128            // nodes per bucket
#define NB       782            // ceil(100000/128)
#define G1_TILES 782            // gemm1: 128 rows per block
#define E_BLOCKS 6250           // 1.6M / 256
#define MIX_TOT  7038           // 782*9 ; bid%9==0 -> gemm tile, else scatter

typedef short v8s __attribute__((ext_vector_type(8)));
typedef float v4f __attribute__((ext_vector_type(4)));

__device__ __forceinline__ short f2bf(float f) {
    unsigned u = __float_as_uint(f);
    u += 0x7fffu + ((u >> 16) & 1u);
    return (short)(u >> 16);
}

__device__ __forceinline__ v8s pack8(float4 a, float4 b) {
    v8s r;
    r[0] = f2bf(a.x); r[1] = f2bf(a.y); r[2] = f2bf(a.z); r[3] = f2bf(a.w);
    r[4] = f2bf(b.x); r[5] = f2bf(b.y); r[6] = f2bf(b.z); r[7] = f2bf(b.w);
    return r;
}

// ---------------- GEMM1 tile body: 32 rows/wave, prefetch 1 K-step ----------------

__device__ __forceinline__ void gemm1_tile(int tileIdx, const float* __restrict__ x,
                                           const short* __restrict__ WT1,
                                           unsigned short* __restrict__ m1b) {
    int wave = threadIdx.x >> 6, lane = threadIdx.x & 63;
    int quad = lane >> 4, l16 = lane & 15;
    long rowBase = ((long)tileIdx * 4 + wave) * 32;
    if (rowBase >= N_NODES) return; // N_NODES % 32 == 0

    v4f acc0[8], acc1[8];
#pragma unroll
    for (int t = 0; t < 8; t++) {
        acc0[t] = (v4f){0.f, 0.f, 0.f, 0.f};
        acc1[t] = (v4f){0.f, 0.f, 0.f, 0.f};
    }

    const float* arow0 = x + (rowBase + l16) * (long)F_IN + quad * 8;
    const float* arow1 = arow0 + 16 * F_IN;
    const short* brow  = WT1 + l16 * F_IN + quad * 8;

    float4 a00 = *reinterpret_cast<const float4*>(arow0 + 0);
    float4 a01 = *reinterpret_cast<const float4*>(arow0 + 4);
    float4 a10 = *reinterpret_cast<const float4*>(arow1 + 0);
    float4 a11 = *reinterpret_cast<const float4*>(arow1 + 4);
    v8s bf[8];
#pragma unroll
    for (int t = 0; t < 8; t++)
        bf[t] = *reinterpret_cast<const v8s*>(brow + t * 16 * F_IN);

#pragma unroll
    for (int it = 0; it < 16; it++) {
        int kn = (it + 1) * 32;
        float4 n00, n01, n10, n11;
        v8s nb[8];
        if (it < 15) {
            n00 = *reinterpret_cast<const float4*>(arow0 + kn);
            n01 = *reinterpret_cast<const float4*>(arow0 + kn + 4);
            n10 = *reinterpret_cast<const float4*>(arow1 + kn);
            n11 = *reinterpret_cast<const float4*>(arow1 + kn + 4);
#pragma unroll
            for (int t = 0; t < 8; t++)
                nb[t] = *reinterpret_cast<const v8s*>(brow + t * 16 * F_IN + kn);
        }
        v8s af0 = pack8(a00, a01);
        v8s af1 = pack8(a10, a11);
#pragma unroll
        for (int t = 0; t < 8; t++) {
            acc0[t] = __builtin_amdgcn_mfma_f32_16x16x32_bf16(af0, bf[t], acc0[t], 0, 0, 0);
            acc1[t] = __builtin_amdgcn_mfma_f32_16x16x32_bf16(af1, bf[t], acc1[t], 0, 0, 0);
        }
        if (it < 15) {
            a00 = n00; a01 = n01; a10 = n10; a11 = n11;
#pragma unroll
            for (int t = 0; t < 8; t++) bf[t] = nb[t];
        }
    }

#pragma unroll
    for (int t = 0; t < 8; t++)
#pragma unroll
        for (int r = 0; r < 4; r++) {
            m1b[(rowBase + quad * 4 + r) * F_HID + t * 16 + l16] =
                (unsigned short)f2bf(acc0[t][r]);
            m1b[(rowBase + 16 + quad * 4 + r) * F_HID + t * 16 + l16] =
                (unsigned short)f2bf(acc1[t][r]);
        }
}

// ---------------- bucket histogram (b = dst >> 7) ----------------

__global__ void k_histB(const int* __restrict__ dst, int* __restrict__ bcnt) {
    int e = blockIdx.x * blockDim.x + threadIdx.x;
    if (e < N_EDGES) atomicAdd(&bcnt[dst[e] >> 7], 1);
}

// ---------------- bucket scan: 1 block, 1024 threads over NB entries ----------------

__global__ void k_bscan(const int* __restrict__ bcnt, int* __restrict__ boff,
                        int* __restrict__ bcur) {
    __shared__ int sm[1024];
    int tid = threadIdx.x;
    int v = (tid < NB) ? bcnt[tid] : 0;
    sm[tid] = v;
    __syncthreads();
    for (int off = 1; off < 1024; off <<= 1) {
        int t = (tid >= off) ? sm[tid - off] : 0;
        __syncthreads();
        sm[tid] += t;
        __syncthreads();
    }
    if (tid < NB) {
        int r = sm[tid] - v; // exclusive
        boff[tid] = r;
        bcur[tid] = r;
    }
    if (tid == NB - 1) boff[NB] = sm[tid];
}

// ---------------- MIX: gemm1 tiles interleaved 1:8 with bucket scatter ----------------
// srec[pos] = { src | (localdst<<17), bits(w) } — dense append per bucket.

__global__ __launch_bounds__(256) void k_mix(const float* __restrict__ x,
                                             const short* __restrict__ WT1,
                                             unsigned short* __restrict__ m1b,
                                             const int* __restrict__ src,
                                             const int* __restrict__ dst,
                                             const float* __restrict__ ew,
                                             int* __restrict__ bcur,
                                             int2* __restrict__ srec) {
    int bid = blockIdx.x;
    if (bid % 9 == 0) {
        gemm1_tile(bid / 9, x, WT1, m1b); // bid/9 in [0, 782)
    } else {
        int sidx = bid - bid / 9 - 1;     // 0 .. 6255
        int e = sidx * 256 + threadIdx.x;
        if (e < N_EDGES) {
            int d = dst[e];
            int pos = atomicAdd(&bcur[d >> 7], 1);
            srec[pos] = make_int2(src[e] | ((d & 127) << 17), __float_as_int(ew[e]));
        }
    }
}

// ---------------- weight transpose+convert ----------------

__global__ void k_convW(const float* __restrict__ W1, short* __restrict__ WT1,
                        const float* __restrict__ W2, short* __restrict__ WT2) {
    int i = blockIdx.x * blockDim.x + threadIdx.x;
    if (i < F_IN * F_HID) {            // i = n*512 + k
        int n = i >> 9, k = i & 511;
        WT1[i] = f2bf(W1[k * F_HID + n]);
    } else {
        int j = i - F_IN * F_HID;      // j = n*128 + k
        if (j < F_OUT_PAD * F_HID) {
            int n = j >> 7, k = j & 127;
            WT2[j] = (n < F_OUT) ? f2bf(W2[k * F_OUT + n]) : (short)0;
        }
    }
}

// ---------------- fused layer-1 aggregation: 1 block per bucket ----------------
// LDS acc[128 nodes][128 feats] fp32 (64 KB). 8 waves stream staged edges,
// gather m1 rows (2 bf16/lane), atomicAdd into LDS; epilogue bias+ReLU -> h.

__global__ __launch_bounds__(512) void k_agg1f(const int2* __restrict__ srec,
                                               const int* __restrict__ boff,
                                               const unsigned* __restrict__ m1u,
                                               const float* __restrict__ b1,
                                               unsigned* __restrict__ h) {
    __shared__ float acc[BSZ * F_HID]; // 65536 B
    int b = blockIdx.x;
    int tid = threadIdx.x, wave = tid >> 6, lane = tid & 63;

    for (int j = tid; j < BSZ * F_HID; j += 512) acc[j] = 0.f;
    __syncthreads();

    int s0 = boff[b], e0 = boff[b + 1];
    int i = s0 + wave;
    for (; i + 8 < e0; i += 16) {
        int2 r0 = srec[i];
        int2 r1 = srec[i + 8];
        unsigned u0 = m1u[(long)(r0.x & 0x1FFFF) * 64 + lane];
        unsigned u1 = m1u[(long)(r1.x & 0x1FFFF) * 64 + lane];
        int ld0 = (r0.x >> 17) & 127, ld1 = (r1.x >> 17) & 127;
        float w0 = __int_as_float(r0.y), w1 = __int_as_float(r1.y);
        atomicAdd(&acc[ld0 * F_HID + 2 * lane],     w0 * __uint_as_float(u0 << 16));
        atomicAdd(&acc[ld0 * F_HID + 2 * lane + 1], w0 * __uint_as_float(u0 & 0xffff0000u));
        atomicAdd(&acc[ld1 * F_HID + 2 * lane],     w1 * __uint_as_float(u1 << 16));
        atomicAdd(&acc[ld1 * F_HID + 2 * lane + 1], w1 * __uint_as_float(u1 & 0xffff0000u));
    }
    if (i < e0) {
        int2 r = srec[i];
        unsigned u = m1u[(long)(r.x & 0x1FFFF) * 64 + lane];
        int ld = (r.x >> 17) & 127;
        float w = __int_as_float(r.y);
        atomicAdd(&acc[ld * F_HID + 2 * lane],     w * __uint_as_float(u << 16));
        atomicAdd(&acc[ld * F_HID + 2 * lane + 1], w * __uint_as_float(u & 0xffff0000u));
    }
    __syncthreads();

    float bx = b1[2 * lane], by = b1[2 * lane + 1];
    for (int n = wave * 16; n < wave * 16 + 16; n++) {
        long node = (long)b * BSZ + n;
        if (node >= N_NODES) break;
        float vx = fmaxf(acc[n * F_HID + 2 * lane] + bx, 0.f);
        float vy = fmaxf(acc[n * F_HID + 2 * lane + 1] + by, 0.f);
        unsigned packed = (unsigned)(unsigned short)f2bf(vx) |
                          ((unsigned)(unsigned short)f2bf(vy) << 16);
        h[node * 64 + lane] = packed;
    }
}

// ---------------- GEMM2: m2b[100000,64] (bf16) = h @ W2; cols 40..63 zero ----------

__global__ __launch_bounds__(256) void k_gemm2(const unsigned short* __restrict__ h,
                                               const short* __restrict__ WT2,
                                               unsigned short* __restrict__ m2b) {
    int wave = threadIdx.x >> 6, lane = threadIdx.x & 63;
    int quad = lane >> 4, l16 = lane & 15;
    long rowBase = ((long)blockIdx.x * 4 + wave) * 16;
    if (rowBase >= N_NODES) return;

    v4f acc[3];
#pragma unroll
    for (int t = 0; t < 3; t++) acc[t] = (v4f){0.f, 0.f, 0.f, 0.f};

    const short* arow = (const short*)h + (rowBase + l16) * (long)F_HID + quad * 8;
    const short* brow = WT2 + l16 * F_HID + quad * 8;
#pragma unroll
    for (int k0 = 0; k0 < F_HID; k0 += 32) {
        v8s af = *reinterpret_cast<const v8s*>(arow + k0);
#pragma unroll
        for (int t = 0; t < 3; t++) {
            v8s bf = *reinterpret_cast<const v8s*>(brow + t * 16 * F_HID + k0);
            acc[t] = __builtin_amdgcn_mfma_f32_16x16x32_bf16(af, bf, acc[t], 0, 0, 0);
        }
    }
#pragma unroll
    for (int r = 0; r < 4; r++) {
        long row = rowBase + quad * 4 + r;
#pragma unroll
        for (int t = 0; t < 3; t++)
            m2b[row * 64 + t * 16 + l16] = (unsigned short)f2bf(acc[t][r]);
        m2b[row * 64 + 48 + l16] = 0;
    }
}

// ---------------- fused layer-2 aggregation + bias + log_softmax ----------------
// LDS acc[128 nodes][64 feats] fp32 (32 KB); lane = feat (2-way banks, free).

__global__ __launch_bounds__(512) void k_agg2f(const int2* __restrict__ srec,
                                               const int* __restrict__ boff,
                                               const unsigned short* __restrict__ m2b,
                                               const float* __restrict__ b2,
                                               float* __restrict__ out) {
    __shared__ float acc[BSZ * 64]; // 32768 B
    int b = blockIdx.x;
    int tid = threadIdx.x, wave = tid >> 6, lane = tid & 63;

    for (int j = tid; j < BSZ * 64; j += 512) acc[j] = 0.f;
    __syncthreads();

    int s0 = boff[b], e0 = boff[b + 1];
    int i = s0 + wave;
    for (; i + 8 < e0; i += 16) {
        int2 r0 = srec[i];
        int2 r1 = srec[i + 8];
        unsigned short u0 = m2b[(long)(r0.x & 0x1FFFF) * 64 + lane];
        unsigned short u1 = m2b[(long)(r1.x & 0x1FFFF) * 64 + lane];
        int ld0 = (r0.x >> 17) & 127, ld1 = (r1.x >> 17) & 127;
        atomicAdd(&acc[ld0 * 64 + lane],
                  __int_as_float(r0.y) * __uint_as_float((unsigned)u0 << 16));
        atomicAdd(&acc[ld1 * 64 + lane],
                  __int_as_float(r1.y) * __uint_as_float((unsigned)u1 << 16));
    }
    if (i < e0) {
        int2 r = srec[i];
        unsigned short u = m2b[(long)(r.x & 0x1FFFF) * 64 + lane];
        int ld = (r.x >> 17) & 127;
        atomicAdd(&acc[ld * 64 + lane],
                  __int_as_float(r.y) * __uint_as_float((unsigned)u << 16));
    }
    __syncthreads();

    float bias = (lane < F_OUT) ? b2[lane] : 0.f;
    for (int n = wave; n < BSZ; n += 8) {
        long node = (long)b * BSZ + n;
        if (node >= N_NODES) continue;
        float v = acc[n * 64 + lane] + bias;
        float p = (lane < F_OUT) ? v : -3.4e38f;
#pragma unroll
        for (int off = 32; off; off >>= 1) p = fmaxf(p, __shfl_xor(p, off));
        float ex = (lane < F_OUT) ? __expf(v - p) : 0.f;
        float s = ex;
#pragma unroll
        for (int off = 32; off; off >>= 1) s += __shfl_xor(s, off);
        if (lane < F_OUT) out[node * F_OUT + lane] = v - p - __logf(s);
    }
}

// ---------------- launch ----------------

extern "C" void kernel_launch(void* const* d_in, const int* in_sizes, int n_in,
                              void* d_out, int out_size, void* d_ws, size_t ws_size,
                              hipStream_t stream) {
    const float* x  = (const float*)d_in[0];
    const int* ei   = (const int*)d_in[1]; // [2, E]: src then dst (int32)
    const int* src  = ei;
    const int* dst  = ei + N_EDGES;
    const float* ew = (const float*)d_in[2];
    const float* W1 = (const float*)d_in[3];
    const float* b1 = (const float*)d_in[4];
    const float* W2 = (const float*)d_in[5];
    const float* b2 = (const float*)d_in[6];
    float* out = (float*)d_out;

    char* ws = (char*)d_ws;
    size_t off = 0;
    auto alloc = [&](size_t bytes) {
        void* p = ws + off;
        off += (bytes + 255) & ~(size_t)255;
        return p;
    };
    unsigned short* m1b  = (unsigned short*)alloc((size_t)N_NODES * F_HID * 2); // 25.6 MB
    unsigned int*   h    = (unsigned int*)alloc((size_t)N_NODES * F_HID * 2);   // 25.6 MB
    unsigned short* m2b  = (unsigned short*)alloc((size_t)N_NODES * 64 * 2);    // 12.8 MB
    int2*           srec = (int2*)alloc((size_t)N_EDGES * 8);                   // 12.8 MB
    int*            bcnt = (int*)alloc((NB + 1) * 4);
    int*            boff = (int*)alloc((NB + 1) * 4);
    int*            bcur = (int*)alloc((NB + 1) * 4);
    short*          WT1  = (short*)alloc((size_t)F_HID * F_IN * 2);
    short*          WT2  = (short*)alloc((size_t)F_OUT_PAD * F_HID * 2);

    hipMemsetAsync(bcnt, 0, (NB + 1) * 4, stream);

    int convTot = F_IN * F_HID + F_OUT_PAD * F_HID;
    k_convW<<<(convTot + 255) / 256, 256, 0, stream>>>(W1, WT1, W2, WT2);

    k_histB<<<E_BLOCKS, 256, 0, stream>>>(dst, bcnt);
    k_bscan<<<1, 1024, 0, stream>>>(bcnt, boff, bcur);

    // gemm1 (every 9th block) interleaved with bucket scatter
    k_mix<<<MIX_TOT, 256, 0, stream>>>(x, WT1, m1b, src, dst, ew, bcur, srec);

    k_agg1f<<<NB, 512, 0, stream>>>(srec, boff, (const unsigned*)m1b, b1, h);
    k_gemm2<<<(N_NODES + 63) / 64, 256, 0, stream>>>((const unsigned short*)h, WT2, m2b);
    k_agg2f<<<NB, 512, 0, stream>>>(srec, boff, m2b, b2, out);
}

// Round 6
// 664.264 us; speedup vs baseline: 4.6096x; 4.6096x over previous
//
#include <hip/hip_runtime.h>
#include <hip/hip_bf16.h>
#include <cstdint>

#define N_NODES 100000
#define N_EDGES 1600000
#define F_IN    512
#define F_HID   128
#define F_OUT   40
#define F_OUT_PAD 48

typedef short v8s __attribute__((ext_vector_type(8)));
typedef float v4f __attribute__((ext_vector_type(4)));

__device__ __forceinline__ short f2bf(float f) {
    unsigned u = __float_as_uint(f);
    u += 0x7fffu + ((u >> 16) & 1u);
    return (short)(u >> 16);
}

__device__ __forceinline__ v8s pack8(float4 a, float4 b) {
    v8s r;
    r[0] = f2bf(a.x); r[1] = f2bf(a.y); r[2] = f2bf(a.z); r[3] = f2bf(a.w);
    r[4] = f2bf(b.x); r[5] = f2bf(b.y); r[6] = f2bf(b.z); r[7] = f2bf(b.w);
    return r;
}

// async 16B global->LDS (direct-to-shared DMA; LDS dest = wave-uniform base + lane*16)
__device__ __forceinline__ void gload16(const void* g, void* l) {
    __builtin_amdgcn_global_load_lds(
        (const __attribute__((address_space(1))) void*)g,
        (__attribute__((address_space(3))) void*)l, 16, 0, 0);
}

// ---------------- CSR build: histogram -> scan -> scatter ----------------

__global__ void k_hist(const int* __restrict__ dst, int* __restrict__ deg) {
    int e = blockIdx.x * blockDim.x + threadIdx.x;
    if (e < N_EDGES) atomicAdd(&deg[dst[e]], 1);
}

__global__ void k_scan1(const int* __restrict__ deg, int* __restrict__ rowptr,
                        int* __restrict__ bsums) {
    __shared__ int sm[1024];
    int tid = threadIdx.x;
    int i = blockIdx.x * 1024 + tid;
    int v = (i < N_NODES) ? deg[i] : 0;
    sm[tid] = v;
    __syncthreads();
    for (int off = 1; off < 1024; off <<= 1) {
        int t = (tid >= off) ? sm[tid - off] : 0;
        __syncthreads();
        sm[tid] += t;
        __syncthreads();
    }
    if (i < N_NODES) rowptr[i] = sm[tid] - v;     // exclusive
    if (tid == 1023) bsums[blockIdx.x] = sm[tid]; // block total
}

__global__ void k_scan2(int* bsums, int nb) {
    __shared__ int sm[128];
    int tid = threadIdx.x;
    int v = (tid < nb) ? bsums[tid] : 0;
    sm[tid] = v;
    __syncthreads();
    for (int off = 1; off < 128; off <<= 1) {
        int t = (tid >= off) ? sm[tid - off] : 0;
        __syncthreads();
        sm[tid] += t;
        __syncthreads();
    }
    if (tid < nb) bsums[tid] = sm[tid] - v; // exclusive
}

__global__ void k_scan3(int* __restrict__ rowptr, int* __restrict__ cursor,
                        const int* __restrict__ bsums) {
    int i = blockIdx.x * blockDim.x + threadIdx.x;
    if (i < N_NODES) {
        int r = rowptr[i] + bsums[i >> 10];
        rowptr[i] = r;
        cursor[i] = r;
    }
}

__global__ void k_scatter(const int* __restrict__ src, const int* __restrict__ dst,
                          const float* __restrict__ w, int* __restrict__ cursor,
                          int2* __restrict__ rec) {
    int e = blockIdx.x * blockDim.x + threadIdx.x;
    if (e < N_EDGES) {
        int d = dst[e];
        int pos = atomicAdd(&cursor[d], 1);
        rec[pos] = make_int2(src[e], __float_as_int(w[e]));
    }
}

// ---------------- weight transpose+convert ----------------

__global__ void k_convW(const float* __restrict__ W1, short* __restrict__ WT1,
                        const float* __restrict__ W2, short* __restrict__ WT2) {
    int i = blockIdx.x * blockDim.x + threadIdx.x;
    if (i < F_IN * F_HID) {            // i = n*512 + k
        int n = i >> 9, k = i & 511;
        WT1[i] = f2bf(W1[k * F_HID + n]);
    } else {
        int j = i - F_IN * F_HID;      // j = n*128 + k
        if (j < F_OUT_PAD * F_HID) {
            int n = j >> 7, k = j & 127;
            WT2[j] = (n < F_OUT) ? f2bf(W2[k * F_OUT + n]) : (short)0;
        }
    }
}

// ---------------- GEMM1 (LDS-staged, m97-style): m1b = x @ W1 ----------------
// Block: 256 thr (4 waves), tile M=64 x N=128, BK=32, double-buffered
// global_load_lds staging. XOR swizzle keeps DMA contiguous and LDS reads
// <=2-way (free). A staged fp32 (converted post-LDS-read), B staged bf16.

__global__ __launch_bounds__(256) void k_gemm1(const float* __restrict__ x,
                                               const short* __restrict__ WT1,
                                               unsigned short* __restrict__ m1b) {
    __shared__ __align__(16) float aBuf[2][64 * 32];  // 2 x 8 KB
    __shared__ __align__(16) short bBuf[2][128 * 32]; // 2 x 8 KB
    int tid = threadIdx.x, w = tid >> 6, lane = tid & 63;
    int quad = lane >> 4, l16 = lane & 15;
    long rowBase = (long)blockIdx.x * 64;

    // staging lane decomposition
    int ar = lane >> 3, ac = lane & 7; // A: 8 rows x 8 kblocks(16B=4 floats)
    int br = lane >> 2, bc = lane & 3; // B: 16 rows x 4 kblocks(16B=8 bf16)

    v4f acc[8];
#pragma unroll
    for (int t = 0; t < 8; t++) acc[t] = (v4f){0.f, 0.f, 0.f, 0.f};

    // --- stage chunk kc into buffer buf ---
    auto stage = [&](int kc, int buf) {
#pragma unroll
        for (int i = 0; i < 2; i++) { // A: wave w stages rows w*16 .. +15
            int rl = w * 16 + i * 8 + ar;
            long rg = rowBase + rl;
            if (rg > N_NODES - 1) rg = N_NODES - 1; // tail clamp (dup, harmless)
            const float* gp = x + rg * F_IN + kc * 32 + ((ac ^ (rl & 7)) << 2);
            gload16(gp, &aBuf[buf][(w * 16 + i * 8) * 32]);
        }
#pragma unroll
        for (int i = 0; i < 2; i++) { // B: wave w stages n-rows w*32 .. +31
            int n = w * 32 + i * 16 + br;
            const short* gp = WT1 + n * F_IN + kc * 32 + ((bc ^ ((n >> 1) & 3)) << 3);
            gload16(gp, &bBuf[buf][(w * 32 + i * 16) * 32]);
        }
    };

    stage(0, 0);
#pragma unroll
    for (int kc = 0; kc < 16; kc++) {
        __syncthreads(); // drains global_load_lds (vmcnt) + all-wave arrival
        int buf = kc & 1;
        if (kc < 15) stage(kc + 1, buf ^ 1);
        // A-frag: rows w*16+l16, k = quad*8+j ; swizzled kblock p = (2q)^(r&7)
        int arow = w * 16 + l16;
        int p0 = (2 * quad) ^ (l16 & 7);
        float4 av0 = *(const float4*)&aBuf[buf][arow * 32 + p0 * 4];
        float4 av1 = *(const float4*)&aBuf[buf][arow * 32 + (p0 ^ 1) * 4];
        v8s af = pack8(av0, av1);
#pragma unroll
        for (int t = 0; t < 8; t++) {
            int n = t * 16 + l16;
            int p = quad ^ ((n >> 1) & 3);
            v8s bf = *(const v8s*)&bBuf[buf][n * 32 + p * 8];
            acc[t] = __builtin_amdgcn_mfma_f32_16x16x32_bf16(af, bf, acc[t], 0, 0, 0);
        }
    }

#pragma unroll
    for (int t = 0; t < 8; t++)
#pragma unroll
        for (int r = 0; r < 4; r++) {
            long row = rowBase + w * 16 + quad * 4 + r;
            if (row < N_NODES)
                m1b[row * F_HID + t * 16 + l16] = (unsigned short)f2bf(acc[t][r]);
        }
}

// ---------------- layer-1 aggregation: wave/node, bf16x2 per lane, 4-edge unroll ----

__global__ void k_agg1(const int2* __restrict__ rec, const int* __restrict__ rowptr,
                       const int* __restrict__ deg, const unsigned* __restrict__ m1u,
                       const float* __restrict__ b1, unsigned* __restrict__ h) {
    int node = blockIdx.x * 4 + (threadIdx.x >> 6);
    int lane = threadIdx.x & 63;
    if (node >= N_NODES) return;
    int start = rowptr[node], cnt = deg[node];

    float ax0 = 0.f, ay0 = 0.f, ax1 = 0.f, ay1 = 0.f;
    float ax2 = 0.f, ay2 = 0.f, ax3 = 0.f, ay3 = 0.f;
    int i = 0;
    for (; i + 4 <= cnt; i += 4) {
        int2 r0 = rec[start + i + 0];
        int2 r1 = rec[start + i + 1];
        int2 r2 = rec[start + i + 2];
        int2 r3 = rec[start + i + 3];
        unsigned u0 = m1u[(long)r0.x * 64 + lane];
        unsigned u1 = m1u[(long)r1.x * 64 + lane];
        unsigned u2 = m1u[(long)r2.x * 64 + lane];
        unsigned u3 = m1u[(long)r3.x * 64 + lane];
        float w0 = __int_as_float(r0.y), w1 = __int_as_float(r1.y);
        float w2 = __int_as_float(r2.y), w3 = __int_as_float(r3.y);
        ax0 = fmaf(w0, __uint_as_float(u0 << 16), ax0);
        ay0 = fmaf(w0, __uint_as_float(u0 & 0xffff0000u), ay0);
        ax1 = fmaf(w1, __uint_as_float(u1 << 16), ax1);
        ay1 = fmaf(w1, __uint_as_float(u1 & 0xffff0000u), ay1);
        ax2 = fmaf(w2, __uint_as_float(u2 << 16), ax2);
        ay2 = fmaf(w2, __uint_as_float(u2 & 0xffff0000u), ay2);
        ax3 = fmaf(w3, __uint_as_float(u3 << 16), ax3);
        ay3 = fmaf(w3, __uint_as_float(u3 & 0xffff0000u), ay3);
    }
    for (; i < cnt; i++) {
        int2 r = rec[start + i];
        unsigned u = m1u[(long)r.x * 64 + lane];
        float w = __int_as_float(r.y);
        ax0 = fmaf(w, __uint_as_float(u << 16), ax0);
        ay0 = fmaf(w, __uint_as_float(u & 0xffff0000u), ay0);
    }
    float accx = (ax0 + ax1) + (ax2 + ax3) + b1[2 * lane];
    float accy = (ay0 + ay1) + (ay2 + ay3) + b1[2 * lane + 1];
    accx = fmaxf(accx, 0.f);
    accy = fmaxf(accy, 0.f);
    unsigned packed = (unsigned)(unsigned short)f2bf(accx) |
                      ((unsigned)(unsigned short)f2bf(accy) << 16);
    h[(long)node * 64 + lane] = packed; // h is bf16[100000][128]
}

// ---------------- GEMM2: m2b[100000,64] (bf16) = h @ W2; cols 40..63 zero ----------

__global__ __launch_bounds__(256) void k_gemm2(const unsigned short* __restrict__ h,
                                               const short* __restrict__ WT2,
                                               unsigned short* __restrict__ m2b) {
    int wave = threadIdx.x >> 6, lane = threadIdx.x & 63;
    int quad = lane >> 4, l16 = lane & 15;
    long rowBase = ((long)blockIdx.x * 4 + wave) * 16;
    if (rowBase >= N_NODES) return;

    v4f acc[3];
#pragma unroll
    for (int t = 0; t < 3; t++) acc[t] = (v4f){0.f, 0.f, 0.f, 0.f};

    const short* arow = (const short*)h + (rowBase + l16) * (long)F_HID + quad * 8;
    const short* brow = WT2 + l16 * F_HID + quad * 8;
#pragma unroll
    for (int k0 = 0; k0 < F_HID; k0 += 32) {
        v8s af = *reinterpret_cast<const v8s*>(arow + k0);
#pragma unroll
        for (int t = 0; t < 3; t++) {
            v8s bf = *reinterpret_cast<const v8s*>(brow + t * 16 * F_HID + k0);
            acc[t] = __builtin_amdgcn_mfma_f32_16x16x32_bf16(af, bf, acc[t], 0, 0, 0);
        }
    }
#pragma unroll
    for (int r = 0; r < 4; r++) {
        long row = rowBase + quad * 4 + r;
#pragma unroll
        for (int t = 0; t < 3; t++)
            m2b[row * 64 + t * 16 + l16] = (unsigned short)f2bf(acc[t][r]);
        m2b[row * 64 + 48 + l16] = 0;
    }
}

// ---------------- layer-2 aggregation + bias + log_softmax (bf16 gather) ----------

__global__ void k_agg2(const int2* __restrict__ rec, const int* __restrict__ rowptr,
                       const int* __restrict__ deg, const unsigned short* __restrict__ m2b,
                       const float* __restrict__ b2, float* __restrict__ out) {
    int node = blockIdx.x * 4 + (threadIdx.x >> 6);
    int lane = threadIdx.x & 63;
    if (node >= N_NODES) return;
    int start = rowptr[node], cnt = deg[node];

    float a0 = 0.f, a1 = 0.f, a2 = 0.f, a3 = 0.f;
    int i = 0;
    for (; i + 4 <= cnt; i += 4) {
        int2 r0 = rec[start + i + 0];
        int2 r1 = rec[start + i + 1];
        int2 r2 = rec[start + i + 2];
        int2 r3 = rec[start + i + 3];
        unsigned short u0 = m2b[(long)r0.x * 64 + lane];
        unsigned short u1 = m2b[(long)r1.x * 64 + lane];
        unsigned short u2 = m2b[(long)r2.x * 64 + lane];
        unsigned short u3 = m2b[(long)r3.x * 64 + lane];
        a0 = fmaf(__int_as_float(r0.y), __uint_as_float((unsigned)u0 << 16), a0);
        a1 = fmaf(__int_as_float(r1.y), __uint_as_float((unsigned)u1 << 16), a1);
        a2 = fmaf(__int_as_float(r2.y), __uint_as_float((unsigned)u2 << 16), a2);
        a3 = fmaf(__int_as_float(r3.y), __uint_as_float((unsigned)u3 << 16), a3);
    }
    for (; i < cnt; i++) {
        int2 r = rec[start + i];
        unsigned short u = m2b[(long)r.x * 64 + lane];
        a0 = fmaf(__int_as_float(r.y), __uint_as_float((unsigned)u << 16), a0);
    }
    float acc = (a0 + a1) + (a2 + a3);
    if (lane < F_OUT) acc += b2[lane];
    float p = (lane < F_OUT) ? acc : -3.4e38f;
#pragma unroll
    for (int off = 32; off; off >>= 1) p = fmaxf(p, __shfl_xor(p, off));
    float ex = (lane < F_OUT) ? __expf(acc - p) : 0.f;
    float s = ex;
#pragma unroll
    for (int off = 32; off; off >>= 1) s += __shfl_xor(s, off);
    if (lane < F_OUT) out[(long)node * F_OUT + lane] = acc - p - __logf(s);
}

// ---------------- launch ----------------

extern "C" void kernel_launch(void* const* d_in, const int* in_sizes, int n_in,
                              void* d_out, int out_size, void* d_ws, size_t ws_size,
                              hipStream_t stream) {
    const float* x  = (const float*)d_in[0];
    const int* ei   = (const int*)d_in[1]; // [2, E]: src then dst (int32)
    const int* src  = ei;
    const int* dst  = ei + N_EDGES;
    const float* ew = (const float*)d_in[2];
    const float* W1 = (const float*)d_in[3];
    const float* b1 = (const float*)d_in[4];
    const float* W2 = (const float*)d_in[5];
    const float* b2 = (const float*)d_in[6];
    float* out = (float*)d_out;

    char* ws = (char*)d_ws;
    size_t off = 0;
    auto alloc = [&](size_t bytes) {
        void* p = ws + off;
        off += (bytes + 255) & ~(size_t)255;
        return p;
    };
    unsigned short* m1b  = (unsigned short*)alloc((size_t)N_NODES * F_HID * 2); // 25.6 MB
    unsigned int*   h    = (unsigned int*)alloc((size_t)N_NODES * F_HID * 2);   // 25.6 MB
    unsigned short* m2b  = (unsigned short*)alloc((size_t)N_NODES * 64 * 2);    // 12.8 MB
    int2*           rec  = (int2*)alloc((size_t)N_EDGES * 8);                   // 12.8 MB
    int*          rowptr = (int*)alloc((size_t)N_NODES * 4);
    int*          deg    = (int*)alloc((size_t)N_NODES * 4);
    int*          cursor = (int*)alloc((size_t)N_NODES * 4);
    int*          bsums  = (int*)alloc(1024 * 4);
    short*        WT1    = (short*)alloc((size_t)F_HID * F_IN * 2);
    short*        WT2    = (short*)alloc((size_t)F_OUT_PAD * F_HID * 2);

    hipMemsetAsync(deg, 0, (size_t)N_NODES * 4, stream);

    int convTot = F_IN * F_HID + F_OUT_PAD * F_HID;
    k_convW<<<(convTot + 255) / 256, 256, 0, stream>>>(W1, WT1, W2, WT2);

    k_hist<<<(N_EDGES + 255) / 256, 256, 0, stream>>>(dst, deg);
    int nb = (N_NODES + 1023) / 1024; // 98
    k_scan1<<<nb, 1024, 0, stream>>>(deg, rowptr, bsums);
    k_scan2<<<1, 128, 0, stream>>>(bsums, nb);
    k_scan3<<<(N_NODES + 255) / 256, 256, 0, stream>>>(rowptr, cursor, bsums);
    k_scatter<<<(N_EDGES + 255) / 256, 256, 0, stream>>>(src, dst, ew, cursor, rec);

    k_gemm1<<<(N_NODES + 63) / 64, 256, 0, stream>>>(x, WT1, m1b);
    k_agg1<<<(N_NODES + 3) / 4, 256, 0, stream>>>(rec, rowptr, deg, (const unsigned*)m1b, b1, h);
    k_gemm2<<<(N_NODES + 63) / 64, 256, 0, stream>>>((const unsigned short*)h, WT2, m2b);
    k_agg2<<<(N_NODES + 3) / 4, 256, 0, stream>>>(rec, rowptr, deg, m2b, b2, out);
}